// Round 15
// baseline (11839.266 us; speedup 1.0000x reference)
//
#include <hip/hip_runtime.h>
#include <math.h>

#define NSAMP  2048
#define LSTEPS 100
#define DDIM   512
#define TDIM   1024
#define SB     8      // samples per block
#define NTHR   512    // threads per block
#define JJ     2      // output neurons per thread (tid, tid+512)

// All-fp32 LIF recurrence, bitwise-matched to a mechanical numpy port:
//  - h_t = x_t @ W : np.einsum (optimize=False, never BLAS): nditer puts t
//    innermost -> AXPY over t; per element a FLAT ascending-d single-
//    accumulator chain, separate mul/add roundings (SSE2 baseline, no FMA).
//  - out_prev @ U  : np.matmul -> OpenBLAS sgemm with large-K blocking
//    (any SGEMM_DEFAULT_Q in [512,1023] -> K=1024 splits 512/512):
//    per element, ascending-k fp32 add chain of U[k][j] over spiking k
//    within each panel (0/1 lhs, fma(1,u,acc)==fl(acc+u)); beta=0 store
//    then one rounding at the second-panel merge: C = fl(p0 + p1).
//  - state updates : separately-rounded fp32 ops (ufunc semantics, no FMA).
__global__ __launch_bounds__(NTHR)
void snn_fused(const float* __restrict__ X, const float* __restrict__ W,
               const float* __restrict__ U, float* __restrict__ out)
{
#pragma clang fp contract(off)
    __shared__ float xs[SB][DDIM];                  // 16 KB fp32 x_t
    __shared__ unsigned int msk[2][SB][TDIM / 32];  // 2 KB spike bitmasks

    const int tid = threadIdx.x;
    const int n0  = blockIdx.x * SB;

    float syn[JJ][SB], mem[JJ][SB];
    int   cnt[JJ][SB];
#pragma unroll
    for (int q = 0; q < JJ; ++q)
#pragma unroll
        for (int s = 0; s < SB; ++s) { syn[q][s] = 0.0f; mem[q][s] = 0.0f; cnt[q][s] = 0; }

    ((unsigned int*)msk)[tid] = 0u;   // 2*8*32 = 512 words == NTHR

    const float* w0 = W + tid;
    const float* w1 = W + tid + NTHR;
    const float* u0 = U + tid;
    const float* u1 = U + tid + NTHR;

    int p = 0;
    for (int t = 0; t < LSTEPS; ++t) {
        // ---- stage x_t (fp32, coalesced float4) ----
#pragma unroll
        for (int c = 0; c < 2; ++c) {
            const int cc = tid + c * NTHR;       // 0..1023 chunk id
            const int s  = cc >> 7;
            const int k4 = (cc & 127) << 2;
            *(float4*)&xs[s][k4] =
                *(const float4*)(X + ((size_t)(n0 + s) * LSTEPS + t) * DDIM + k4);
        }
        __syncthreads();

        // ---- h_t[j]: flat ascending-d, single accumulator, mul-then-add ----
        float a32[JJ][SB];
#pragma unroll
        for (int q = 0; q < JJ; ++q)
#pragma unroll
            for (int s = 0; s < SB; ++s) a32[q][s] = 0.0f;

        for (int k4 = 0; k4 < DDIM; k4 += 4) {
            float4 xv[SB];
#pragma unroll
            for (int s = 0; s < SB; ++s) xv[s] = *(const float4*)&xs[s][k4];
            float wv0[4], wv1[4];
#pragma unroll
            for (int e = 0; e < 4; ++e) {
                wv0[e] = w0[(k4 + e) * TDIM];
                wv1[e] = w1[(k4 + e) * TDIM];
            }
#pragma unroll
            for (int s = 0; s < SB; ++s) {
                a32[0][s] = __fadd_rn(a32[0][s], __fmul_rn(wv0[0], xv[s].x));
                a32[0][s] = __fadd_rn(a32[0][s], __fmul_rn(wv0[1], xv[s].y));
                a32[0][s] = __fadd_rn(a32[0][s], __fmul_rn(wv0[2], xv[s].z));
                a32[0][s] = __fadd_rn(a32[0][s], __fmul_rn(wv0[3], xv[s].w));
                a32[1][s] = __fadd_rn(a32[1][s], __fmul_rn(wv1[0], xv[s].x));
                a32[1][s] = __fadd_rn(a32[1][s], __fmul_rn(wv1[1], xv[s].y));
                a32[1][s] = __fadd_rn(a32[1][s], __fmul_rn(wv1[2], xv[s].z));
                a32[1][s] = __fadd_rn(a32[1][s], __fmul_rn(wv1[3], xv[s].w));
            }
        }

        // ---- out_{t-1} @ U: sgemm K-panels 512/512 ----
        float ua[JJ][SB];
#pragma unroll
        for (int q = 0; q < JJ; ++q)
#pragma unroll
            for (int s = 0; s < SB; ++s) ua[q][s] = 0.0f;

        const int wbeg[3] = {0, 16, 32};  // k-bounds 0/512/1024 (/32)
#pragma unroll 1
        for (int panel = 0; panel < 2; ++panel) {
            float pp[JJ][SB];
#pragma unroll
            for (int q = 0; q < JJ; ++q)
#pragma unroll
                for (int s = 0; s < SB; ++s) pp[q][s] = 0.0f;

            for (int w = wbeg[panel]; w < wbeg[panel + 1]; ++w) {
#pragma unroll
                for (int s = 0; s < SB; ++s) {
                    unsigned int bits = msk[p][s][w];   // wave-uniform broadcast
                    while (bits) {
                        const int b = __ffs(bits) - 1;
                        bits &= bits - 1u;
                        const int k = (w << 5) + b;
                        pp[0][s] = __fadd_rn(pp[0][s], u0[k * TDIM]);
                        pp[1][s] = __fadd_rn(pp[1][s], u1[k * TDIM]);
                    }
                }
            }
            // merge: C = p0 (beta=0 store), then C = fl(C + p1)
#pragma unroll
            for (int q = 0; q < JJ; ++q)
#pragma unroll
                for (int s = 0; s < SB; ++s)
                    ua[q][s] = __fadd_rn(ua[q][s], pp[q][s]);
        }

        // ---- LIF update, fp32, each op separately rounded (ufunc semantics) ----
        unsigned int ob0 = 0u, ob1 = 0u;
#pragma unroll
        for (int q = 0; q < JJ; ++q)
#pragma unroll
            for (int s = 0; s < SB; ++s) {
                const float h1 = __fadd_rn(a32[q][s], ua[q][s]);       // h_t + out@U
                const bool  o  = (__fadd_rn(mem[q][s], -1.0f) > 0.0f); // spike(mem-1)
                const float sn = __fadd_rn(__fmul_rn(0.25f, syn[q][s]), h1); // ALPHA*syn+h1
                const float mn = o ? 0.0f : __fadd_rn(mem[q][s], syn[q][s]); // hard reset
                if (o) {
                    cnt[q][s]++;
                    if (q == 0) ob0 |= (1u << s); else ob1 |= (1u << s);
                }
                syn[q][s] = sn;
                mem[q][s] = mn;
            }

        // ---- rebuild spike mask for next step (double-buffered) ----
        if (tid < SB * (TDIM / 32)) ((unsigned int*)(msk[p ^ 1]))[tid] = 0u;
        __syncthreads();
#pragma unroll
        for (int s = 0; s < SB; ++s) {
            if (ob0 & (1u << s)) atomicOr(&msk[p ^ 1][s][tid >> 5], 1u << (tid & 31));
            if (ob1 & (1u << s)) atomicOr(&msk[p ^ 1][s][16 + (tid >> 5)], 1u << (tid & 31));
        }
        __syncthreads();
        p ^= 1;
    }

    // ---- H = count / 100 (0/1 sum exact; one divide rounding) ----
#pragma unroll
    for (int q = 0; q < JJ; ++q)
#pragma unroll
        for (int s = 0; s < SB; ++s)
            out[(size_t)(n0 + s) * TDIM + tid + q * NTHR] =
                __fdiv_rn((float)cnt[q][s], 100.0f);
}

extern "C" void kernel_launch(void* const* d_in, const int* in_sizes, int n_in,
                              void* d_out, int out_size, void* d_ws, size_t ws_size,
                              hipStream_t stream) {
    (void)in_sizes; (void)n_in; (void)out_size; (void)d_ws; (void)ws_size;
    const float* X = (const float*)d_in[0];
    const float* W = (const float*)d_in[1];
    const float* U = (const float*)d_in[2];
    float* outp = (float*)d_out;

    dim3 grid(NSAMP / SB);   // 256 blocks, 1 per CU
    dim3 block(NTHR);        // 512 threads = 8 waves
    hipLaunchKernelGGL(snn_fused, grid, block, 0, stream, X, W, U, outp);
}

// Round 17
// 7765.680 us; speedup vs baseline: 1.5246x; 1.5246x over previous
//
#include <hip/hip_runtime.h>
#include <math.h>

#define NSAMP  2048
#define LSTEPS 100
#define DDIM   512
#define TDIM   1024
#define SB     8      // samples per block
#define NTHR   512    // threads per block (8 waves)
#define JJ     2      // output neurons per thread (tid, tid+512)

// Semantics locked by round-15 pass (absmax==0.0); every float op below is an
// explicit __fmul_rn/__fadd_rn in the exact R15 order:
//  - h_t[j]: flat ascending-d fp32 chain, separate mul/add roundings (no FMA).
//  - out@U : K-panels [0,512),[512,1024); per panel ascending-k fp32 add
//            chain over spiking k; merge = one rounding fl(p0+p1).
//  - state : separately-rounded fp32 ops.
// Structural-only changes vs R15 (order-preserving, no arithmetic change):
//  spike bitmask -> sorted index list (wave compaction), and a 4-wide
//  2-stage software-pipelined gather (loads of group i+1 in flight during
//  adds of group i).
__global__ __launch_bounds__(NTHR)
void snn_fused(const float* __restrict__ X, const float* __restrict__ W,
               const float* __restrict__ U, float* __restrict__ out)
{
#pragma clang fp contract(off)
    __shared__ float xs[SB][DDIM];                   // 16 KB
    __shared__ unsigned int msk[2][SB][TDIM / 32];   // 2 KB
    __shared__ unsigned short klist[2][SB][TDIM];    // 32 KB sorted spike indices
    __shared__ int kcnt[2][SB][2];                   // [0]=count k<512, [1]=total

    const int tid  = threadIdx.x;
    const int lane = tid & 63;
    const int wv   = tid >> 6;
    const int n0   = blockIdx.x * SB;

    float syn[JJ][SB], mem[JJ][SB];
    int   cnt[JJ][SB];
#pragma unroll
    for (int q = 0; q < JJ; ++q)
#pragma unroll
        for (int s = 0; s < SB; ++s) { syn[q][s] = 0.0f; mem[q][s] = 0.0f; cnt[q][s] = 0; }

    ((unsigned int*)msk)[tid] = 0u;          // 512 words == NTHR
    if (tid < 32) ((int*)kcnt)[tid] = 0;     // 2*8*2 ints

    const float* w0 = W + tid;
    const float* w1 = W + tid + NTHR;
    const float* u0 = U + tid;
    const float* u1 = U + tid + NTHR;

    // ascending-k add chains for j0/j1, 4-wide 2-stage pipelined loads.
    // Arithmetic identical to a simple "for i: a += u[k_i]" __fadd_rn chain.
    auto gather2 = [&](const unsigned short* ls, int beg, int end,
                       float& A0, float& A1) {
        float a0 = 0.0f, a1 = 0.0f;
        int i = beg;
        const int n = end - beg;
        if (n >= 4) {
            const int nm = n & ~3;
            int ka = (int)ls[i] << 10,     kb = (int)ls[i + 1] << 10;
            int kc = (int)ls[i + 2] << 10, kd = (int)ls[i + 3] << 10;
            float c0a = u0[ka], c1a = u1[ka];
            float c0b = u0[kb], c1b = u1[kb];
            float c0c = u0[kc], c1c = u1[kc];
            float c0d = u0[kd], c1d = u1[kd];
            for (; i + 4 < beg + nm; i += 4) {
                int ea = (int)ls[i + 4] << 10, eb = (int)ls[i + 5] << 10;
                int ec = (int)ls[i + 6] << 10, ed = (int)ls[i + 7] << 10;
                float d0a = u0[ea], d1a = u1[ea];
                float d0b = u0[eb], d1b = u1[eb];
                float d0c = u0[ec], d1c = u1[ec];
                float d0d = u0[ed], d1d = u1[ed];
                a0 = __fadd_rn(a0, c0a); a1 = __fadd_rn(a1, c1a);   // ascending k
                a0 = __fadd_rn(a0, c0b); a1 = __fadd_rn(a1, c1b);
                a0 = __fadd_rn(a0, c0c); a1 = __fadd_rn(a1, c1c);
                a0 = __fadd_rn(a0, c0d); a1 = __fadd_rn(a1, c1d);
                c0a = d0a; c1a = d1a; c0b = d0b; c1b = d1b;
                c0c = d0c; c1c = d1c; c0d = d0d; c1d = d1d;
            }
            a0 = __fadd_rn(a0, c0a); a1 = __fadd_rn(a1, c1a);
            a0 = __fadd_rn(a0, c0b); a1 = __fadd_rn(a1, c1b);
            a0 = __fadd_rn(a0, c0c); a1 = __fadd_rn(a1, c1c);
            a0 = __fadd_rn(a0, c0d); a1 = __fadd_rn(a1, c1d);
            i = beg + nm;
        }
        for (; i < end; ++i) {
            const int k = (int)ls[i] << 10;
            a0 = __fadd_rn(a0, u0[k]);
            a1 = __fadd_rn(a1, u1[k]);
        }
        A0 = a0; A1 = a1;
    };

    int p = 0;
    for (int t = 0; t < LSTEPS; ++t) {
        // ---- stage x_t (fp32, coalesced float4) ----
#pragma unroll
        for (int c = 0; c < 2; ++c) {
            const int cc = tid + c * NTHR;
            const int s  = cc >> 7;
            const int k4 = (cc & 127) << 2;
            *(float4*)&xs[s][k4] =
                *(const float4*)(X + ((size_t)(n0 + s) * LSTEPS + t) * DDIM + k4);
        }
        __syncthreads();   // staging + prev-iter compaction visibility

        // ---- h_t[j]: flat ascending-d, single accumulator, mul-then-add ----
        float a32[JJ][SB];
#pragma unroll
        for (int q = 0; q < JJ; ++q)
#pragma unroll
            for (int s = 0; s < SB; ++s) a32[q][s] = 0.0f;

        for (int k4 = 0; k4 < DDIM; k4 += 4) {
            float4 xv[SB];
#pragma unroll
            for (int s = 0; s < SB; ++s) xv[s] = *(const float4*)&xs[s][k4];
            float wv0[4], wv1[4];
#pragma unroll
            for (int e = 0; e < 4; ++e) {
                wv0[e] = w0[(k4 + e) * TDIM];
                wv1[e] = w1[(k4 + e) * TDIM];
            }
#pragma unroll
            for (int s = 0; s < SB; ++s) {
                a32[0][s] = __fadd_rn(a32[0][s], __fmul_rn(wv0[0], xv[s].x));
                a32[0][s] = __fadd_rn(a32[0][s], __fmul_rn(wv0[1], xv[s].y));
                a32[0][s] = __fadd_rn(a32[0][s], __fmul_rn(wv0[2], xv[s].z));
                a32[0][s] = __fadd_rn(a32[0][s], __fmul_rn(wv0[3], xv[s].w));
                a32[1][s] = __fadd_rn(a32[1][s], __fmul_rn(wv1[0], xv[s].x));
                a32[1][s] = __fadd_rn(a32[1][s], __fmul_rn(wv1[1], xv[s].y));
                a32[1][s] = __fadd_rn(a32[1][s], __fmul_rn(wv1[2], xv[s].z));
                a32[1][s] = __fadd_rn(a32[1][s], __fmul_rn(wv1[3], xv[s].w));
            }
        }

        // ---- out_{t-1} @ U: list-driven K-panels 512/512 ----
        float ua[JJ][SB];
#pragma unroll 1
        for (int s = 0; s < SB; ++s) {
            const unsigned short* ls = klist[p][s];
            const int clo = kcnt[p][s][0];
            const int ct  = kcnt[p][s][1];
            float q00, q01, q10, q11;
            gather2(ls, 0, clo, q00, q01);    // panel k in [0,512)
            gather2(ls, clo, ct, q10, q11);   // panel k in [512,1024)
            ua[0][s] = __fadd_rn(q00, q10);   // one merge rounding
            ua[1][s] = __fadd_rn(q01, q11);
        }

        // ---- LIF update, fp32, each op separately rounded ----
        unsigned int ob0 = 0u, ob1 = 0u;
#pragma unroll
        for (int q = 0; q < JJ; ++q)
#pragma unroll
            for (int s = 0; s < SB; ++s) {
                const float h1 = __fadd_rn(a32[q][s], ua[q][s]);       // h_t + out@U
                const bool  o  = (__fadd_rn(mem[q][s], -1.0f) > 0.0f); // spike(mem-1)
                const float sn = __fadd_rn(__fmul_rn(0.25f, syn[q][s]), h1); // ALPHA*syn+h1
                const float mn = o ? 0.0f : __fadd_rn(mem[q][s], syn[q][s]); // hard reset
                if (o) {
                    cnt[q][s]++;
                    if (q == 0) ob0 |= (1u << s); else ob1 |= (1u << s);
                }
                syn[q][s] = sn;
                mem[q][s] = mn;
            }

        // ---- rebuild spike mask for next step (double-buffered) ----
        if (tid < SB * (TDIM / 32)) ((unsigned int*)(msk[p ^ 1]))[tid] = 0u;
        __syncthreads();
#pragma unroll
        for (int s = 0; s < SB; ++s) {
            if (ob0 & (1u << s)) atomicOr(&msk[p ^ 1][s][tid >> 5], 1u << (tid & 31));
            if (ob1 & (1u << s)) atomicOr(&msk[p ^ 1][s][16 + (tid >> 5)], 1u << (tid & 31));
        }
        __syncthreads();

        // ---- compact mask -> sorted index list (wave wv handles sample wv) ----
        {
            const int pn = p ^ 1;
            const int s  = wv;
            const unsigned wrd = msk[pn][s][lane >> 1];
            const unsigned w16 = (wrd >> ((lane & 1) * 16)) & 0xFFFFu;
            const int c = __popc(w16);
            int x = c;                      // inclusive scan over 64 lanes
#pragma unroll
            for (int d = 1; d < 64; d <<= 1) {
                int y = __shfl_up(x, d);
                if (lane >= d) x += y;
            }
            int pre = x - c;                // exclusive prefix
            unsigned bits = w16;
            const int base = lane * 16;
            while (bits) {
                const int b = __ffs(bits) - 1;
                bits &= bits - 1u;
                klist[pn][s][pre++] = (unsigned short)(base + b);
            }
            const int clo = __shfl(x, 31);  // spikes with k < 512
            const int ctt = __shfl(x, 63);  // total spikes
            if (lane == 0) { kcnt[pn][s][0] = clo; kcnt[pn][s][1] = ctt; }
        }
        p ^= 1;
    }

    // ---- H = count / 100 (0/1 sum exact; one divide rounding) ----
#pragma unroll
    for (int q = 0; q < JJ; ++q)
#pragma unroll
        for (int s = 0; s < SB; ++s)
            out[(size_t)(n0 + s) * TDIM + tid + q * NTHR] =
                __fdiv_rn((float)cnt[q][s], 100.0f);
}

extern "C" void kernel_launch(void* const* d_in, const int* in_sizes, int n_in,
                              void* d_out, int out_size, void* d_ws, size_t ws_size,
                              hipStream_t stream) {
    (void)in_sizes; (void)n_in; (void)out_size; (void)d_ws; (void)ws_size;
    const float* X = (const float*)d_in[0];
    const float* W = (const float*)d_in[1];
    const float* U = (const float*)d_in[2];
    float* outp = (float*)d_out;

    dim3 grid(NSAMP / SB);   // 256 blocks, 1 per CU
    dim3 block(NTHR);        // 512 threads = 8 waves
    hipLaunchKernelGGL(snn_fused, grid, block, 0, stream, X, W, U, outp);
}